// Round 5
// baseline (8460.892 us; speedup 1.0000x reference)
//
#include <hip/hip_runtime.h>
#include <hip/hip_bf16.h>
#include <stdint.h>

typedef __bf16 bf16x8 __attribute__((ext_vector_type(8)));
typedef __bf16 bf16x4 __attribute__((ext_vector_type(4)));
typedef float  f32x4  __attribute__((ext_vector_type(4)));
typedef unsigned short u16x8 __attribute__((ext_vector_type(8)));

#define MFMA_B16(A_,B_,C_) __builtin_amdgcn_mfma_f32_16x16x32_bf16((A_),(B_),(C_),0,0,0)

static constexpr int TT = 200;
static constexpr int TC = 25;     // T-chunk for encoder
static constexpr int NCH = 8;     // chunks

static __device__ __forceinline__ float sig_f(float x){ return 1.f/(1.f+__expf(-x)); }
static __device__ __forceinline__ float tanh_f(float x){
  float e = __expf(-2.f*fabsf(x));
  float t = (1.f-e)/(1.f+e);
  return x<0.f ? -t : t;
}
static __device__ __forceinline__ float bf2f(unsigned short u){
  union{unsigned int i; float f;} v; v.i = ((unsigned)u)<<16; return v.f;
}
// register-residency barrier: compiler cannot sink/remat the load producing v
static __device__ __forceinline__ void pin8(bf16x8 &v){ asm volatile("" : "+v"(v)); }

// swizzled LDS helpers (row-major tile, byte ^= (row&7)<<4)
static __device__ __forceinline__ int swz_off(int row, int col_bytes, int strideB){
  return (row*strideB + col_bytes) ^ ((row&7)<<4);
}
static __device__ __forceinline__ bf16x8 lds_rdA(const __bf16* buf, int row, int kt, int lq, int strideB){
  return *(const bf16x8*)((const char*)buf + swz_off(row, kt*64 + lq*16, strideB));
}
static __device__ __forceinline__ void lds_wr(__bf16* buf, int row, int dim, int strideB, float v){
  *(__bf16*)((char*)buf + swz_off(row, dim*2, strideB)) = (__bf16)v;
}
// lgkm-only barrier: keeps global loads in flight across the barrier
static __device__ __forceinline__ void lds_barrier(){
  asm volatile("s_waitcnt lgkmcnt(0)" ::: "memory");
  __builtin_amdgcn_s_barrier();
}

// ---------------- K0: f32 -> bf16 ----------------
__global__ void cvt_bf16(const float* __restrict__ s, __bf16* __restrict__ d, int n){
  int i = blockIdx.x*blockDim.x + threadIdx.x;
  int st = gridDim.x*blockDim.x;
  for(; i<n; i+=st) d[i] = (__bf16)s[i];
}

// ---------------- K0b: eps transpose [512][200][64] -> [200][512][64] ------
__global__ void epsT_k(const float4* __restrict__ e, float4* __restrict__ o){
  const int total = 512*200*16;
  int j = blockIdx.x*blockDim.x + threadIdx.x;
  int st = gridDim.x*blockDim.x;
  for(; j<total; j+=st){
    int b = j/3200, rem = j - b*3200;
    int t = rem>>4, dq = rem&15;
    o[((size_t)t*512 + b)*16 + dq] = e[j];
  }
}

// ---------------- K1: gi GEMM (per chunk) ----------------
__global__ __launch_bounds__(256) void gi_gemm(const float* __restrict__ x,
                                               const __bf16* __restrict__ Wall, // [4*768][256]
                                               __bf16* __restrict__ gi, int t0){
  const int tid=threadIdx.x, w=tid>>6, l=tid&63, lr=l&15, lq=l>>4;
  const int cell = blockIdx.y;
  const bool fwd = (cell&1)==0;
  const int m0 = blockIdx.x*64;
  const int tloc = m0>>9, b0 = m0&511;
  const int tabs = fwd ? (t0+tloc) : (TT-1-(t0+tloc));
  const int brow = b0 + w*16 + lr;

  const float* xp = x + (size_t)brow*TT*256 + (size_t)tabs*256 + lq*8;
  bf16x8 a[8];
  #pragma unroll
  for(int kt=0;kt<8;kt++){
    float4 f0 = *(const float4*)(xp + kt*32);
    float4 f1 = *(const float4*)(xp + kt*32 + 4);
    bf16x8 v;
    v[0]=(__bf16)f0.x; v[1]=(__bf16)f0.y; v[2]=(__bf16)f0.z; v[3]=(__bf16)f0.w;
    v[4]=(__bf16)f1.x; v[5]=(__bf16)f1.y; v[6]=(__bf16)f1.z; v[7]=(__bf16)f1.w;
    a[kt]=v;
  }
  const __bf16* Wc = Wall + (size_t)cell*768*256;
  #pragma unroll 1
  for(int nt=0;nt<48;nt++){
    f32x4 acc={};
    const __bf16* bp = Wc + (size_t)(nt*16+lr)*256 + lq*8;
    #pragma unroll
    for(int kt=0;kt<8;kt++)
      acc = MFMA_B16(a[kt], *(const bf16x8*)(bp + kt*32), acc);
    bf16x4 pk;
    pk[0]=(__bf16)acc[0]; pk[1]=(__bf16)acc[1]; pk[2]=(__bf16)acc[2]; pk[3]=(__bf16)acc[3];
    *(bf16x4*)(gi + (((size_t)cell*TC + tloc)*768 + nt*16+lr)*512 + b0 + w*16 + lq*4) = pk;
  }
}

// ---------------- K2: encoder scan (ALL 3 gates PINNED: 192 VGPR) ----------
struct EncP{
  const __bf16* whh;            // [4][768][256]
  const float*  bih[4];
  const float*  bhh[4];
  const __bf16* gi;             // [4][TC][768][512]
  __bf16* henc;                 // [200][512][512]
  float*  hcar;                 // [4][512][256]
  int t0;
};
__global__ __launch_bounds__(512,1) void enc_scan(EncP P){
  const int tid=threadIdx.x, w=tid>>6, l=tid&63, lr=l&15, lq=l>>4;
  const int cell=blockIdx.y, b0=blockIdx.x*16;
  const bool fwd = (cell&1)==0;
  const bool isC = cell>=2;
  const int dim0 = w*32;

  __shared__ __align__(16) __bf16 hA[2][16*256];     // 2 x 8KB
  __shared__ __align__(16) __bf16 giL[2][768*16];    // 2 x 24KB
  __shared__ float blds[1024];

  for(int d=tid; d<256; d+=512){
    blds[d]     = P.bih[cell][d]     + P.bhh[cell][d];
    blds[256+d] = P.bih[cell][256+d] + P.bhh[cell][256+d];
    blds[512+d] = P.bih[cell][512+d];
    blds[768+d] = P.bhh[cell][512+d];
  }
  const __bf16* Wh = P.whh + (size_t)cell*768*256;
  // PINNED all-gate weights (192 VGPRs) — zero weight traffic in the T-loop
  bf16x8 wreg[2][3][8];
  #pragma unroll
  for(int jt=0;jt<2;jt++)
    #pragma unroll
    for(int g=0;g<3;g++)
      #pragma unroll
      for(int kt=0;kt<8;kt++){
        wreg[jt][g][kt] = *(const bf16x8*)(Wh + (size_t)(g*256 + dim0 + jt*16 + lr)*256 + kt*32 + lq*8);
        pin8(wreg[jt][g][kt]);
      }
  // carry
  f32x4 hold[2];
  #pragma unroll
  for(int jt=0;jt<2;jt++)
    #pragma unroll
    for(int rr=0;rr<4;rr++){
      float v = P.hcar[((size_t)cell*512 + b0 + lq*4+rr)*256 + dim0 + jt*16 + lr];
      hold[jt][rr] = v;
      lds_wr(hA[0], lq*4+rr, dim0+jt*16+lr, 512, v);
    }
  // gi staging: wave w stages gate-rows [w*96, w*96+96)
  const int prow = w*96 + (l>>1), phal = l&1;
  const __bf16* gbase = P.gi + ((size_t)cell*TC*768 + prow)*512 + b0 + phal*8;
  u16x8 pf0, pf1, pf2;
  pf0 = *(const u16x8*)(gbase + (size_t)0*768*512 +  0*512);
  pf1 = *(const u16x8*)(gbase + (size_t)0*768*512 + 32*512);
  pf2 = *(const u16x8*)(gbase + (size_t)0*768*512 + 64*512);
  __syncthreads();
  {
    __bf16* gl = giL[0] + prow*16 + phal*8;
    *(u16x8*)(gl)        = pf0;
    *(u16x8*)(gl+32*16)  = pf1;
    *(u16x8*)(gl+64*16)  = pf2;
  }
  { int sn = 1 < TC ? 1 : TC-1;
    pf0 = *(const u16x8*)(gbase + (size_t)sn*768*512 +  0*512);
    pf1 = *(const u16x8*)(gbase + (size_t)sn*768*512 + 32*512);
    pf2 = *(const u16x8*)(gbase + (size_t)sn*768*512 + 64*512);
  }
  lds_barrier();

  int p=0, q=0;
  #pragma unroll 1
  for(int s=0;s<TC;s++){
    const int tglob = P.t0 + s;
    const int tx = fwd ? tglob : (TT-1-tglob);
    if(s+1<TC){
      __bf16* gl = giL[1-q] + prow*16 + phal*8;
      *(u16x8*)(gl)        = pf0;
      *(u16x8*)(gl+32*16)  = pf1;
      *(u16x8*)(gl+64*16)  = pf2;
    }
    { int sn = (s+2<TC) ? s+2 : TC-1;
      pf0 = *(const u16x8*)(gbase + (size_t)sn*768*512 +  0*512);
      pf1 = *(const u16x8*)(gbase + (size_t)sn*768*512 + 32*512);
      pf2 = *(const u16x8*)(gbase + (size_t)sn*768*512 + 64*512);
    }
    const __bf16* gq = giL[q];
    #pragma unroll
    for(int jt=0;jt<2;jt++){
      const int d = dim0 + jt*16 + lr;
      f32x4 aR={}, aZ={}, aH={};
      #pragma unroll
      for(int kt=0;kt<8;kt++){
        bf16x8 frag = lds_rdA(hA[p], lr, kt, lq, 512);
        aR = MFMA_B16(frag, wreg[jt][0][kt], aR);
        aZ = MFMA_B16(frag, wreg[jt][1][kt], aZ);
        aH = MFMA_B16(frag, wreg[jt][2][kt], aH);
      }
      ushort4 gR = *(const ushort4*)(gq + (0*256+d)*16 + lq*4);
      ushort4 gZ = *(const ushort4*)(gq + (1*256+d)*16 + lq*4);
      ushort4 gN = *(const ushort4*)(gq + (2*256+d)*16 + lq*4);
      const float bR=blds[d], bZ=blds[256+d], bI=blds[512+d], bH=blds[768+d];
      const unsigned short* uR=(const unsigned short*)&gR;
      const unsigned short* uZ=(const unsigned short*)&gZ;
      const unsigned short* uN=(const unsigned short*)&gN;
      #pragma unroll
      for(int rr=0;rr<4;rr++){
        float r = sig_f(aR[rr] + bf2f(uR[rr]) + bR);
        float z = sig_f(aZ[rr] + bf2f(uZ[rr]) + bZ);
        float nn= tanh_f(bf2f(uN[rr]) + bI + r*(aH[rr] + bH));
        float h = (1.f-z)*nn + z*hold[jt][rr];
        h = fminf(h, 5.f);
        hold[jt][rr] = h;
        lds_wr(hA[1-p], lq*4+rr, d, 512, h);
      }
    }
    if(isC){
      const int row = l>>2, dgrp = (l&3)*8;
      bf16x8 hv = *(const bf16x8*)((const char*)hA[1-p] +
                    ((row*512 + (dim0+dgrp)*2) ^ ((row&7)<<4)));
      *(bf16x8*)(P.henc + ((size_t)tx*512 + b0 + row)*512 + (cell==3?256:0) + dim0 + dgrp) = hv;
    }
    lds_barrier();
    p ^= 1; q ^= 1;
  }
  #pragma unroll
  for(int jt=0;jt<2;jt++)
    #pragma unroll
    for(int rr=0;rr<4;rr++)
      P.hcar[((size_t)cell*512 + b0 + lq*4+rr)*256 + dim0 + jt*16 + lr] = hold[jt][rr];
}

// ---------------- K3: g0 head ----------------
__global__ void g0_kernel(const float* __restrict__ hgf, const float* __restrict__ hgb,
                          const float* __restrict__ Wm, const float* __restrict__ bm,
                          const float* __restrict__ Wv, const float* __restrict__ bv,
                          const float* __restrict__ eps,
                          float* __restrict__ o_mean, float* __restrict__ o_logv,
                          float* __restrict__ g0){
  int j = blockIdx.x*blockDim.x + threadIdx.x;    // 512*256
  int b = j>>8, d = j&255;
  const float4* hf=(const float4*)(hgf + (size_t)b*256);
  const float4* hb=(const float4*)(hgb + (size_t)b*256);
  const float4* mp=(const float4*)(Wm + (size_t)d*512);
  const float4* vp=(const float4*)(Wv + (size_t)d*512);
  float am=0.f, av=0.f;
  #pragma unroll 4
  for(int k=0;k<64;k++){
    float4 h=hf[k], m=mp[k], v=vp[k];
    am += h.x*m.x + h.y*m.y + h.z*m.z + h.w*m.w;
    av += h.x*v.x + h.y*v.y + h.z*v.z + h.w*v.w;
  }
  #pragma unroll 4
  for(int k=0;k<64;k++){
    float4 h=hb[k], m=mp[64+k], v=vp[64+k];
    am += h.x*m.x + h.y*m.y + h.z*m.z + h.w*m.w;
    av += h.x*v.x + h.y*v.y + h.z*v.z + h.w*v.w;
  }
  float mean = am + bm[d];
  float ev   = __expf(av + bv[d]) + 1e-4f;
  float lv   = __logf(ev);
  o_mean[j]=mean; o_logv[j]=lv;
  g0[j] = eps[j]*sqrtf(ev) + mean;
}

// ---------------- K4: gictT[t][384][512] ----------------
__global__ __launch_bounds__(256,2) void gict_gemm(const __bf16* __restrict__ henc,
                                                   const __bf16* __restrict__ wct,   // [384][576]
                                                   __bf16* __restrict__ gictT){
  const int tid=threadIdx.x, w=tid>>6, l=tid&63, lr=l&15, lq=l>>4;
  const int m0 = blockIdx.x*8 + w*2;
  bf16x8 a[2][16];
  #pragma unroll
  for(int m=0;m<2;m++){
    const __bf16* ap = henc + (size_t)((m0+m)*16 + lr)*512 + lq*8;
    #pragma unroll
    for(int kt=0;kt<16;kt++) a[m][kt] = *(const bf16x8*)(ap + kt*32);
  }
  #pragma unroll 1
  for(int nt=0;nt<24;nt++){
    f32x4 c0={}, c1={};
    const __bf16* bp = wct + (size_t)(nt*16+lr)*576 + lq*8;
    #pragma unroll
    for(int kt=0;kt<16;kt++){
      bf16x8 bb = *(const bf16x8*)(bp + kt*32);
      c0 = MFMA_B16(a[0][kt], bb, c0);
      c1 = MFMA_B16(a[1][kt], bb, c1);
    }
    #pragma unroll
    for(int m=0;m<2;m++){
      f32x4 c = m? c1 : c0;
      int R0 = (m0+m)*16 + lq*4;
      int t  = R0>>9, b = R0&511;
      bf16x4 pk;
      pk[0]=(__bf16)c[0]; pk[1]=(__bf16)c[1]; pk[2]=(__bf16)c[2]; pk[3]=(__bf16)c[3];
      *(bf16x4*)(gictT + ((size_t)t*384 + nt*16+lr)*512 + b) = pk;
    }
  }
}

// ---------------- K5: generator scan ----------------
struct GenP{
  const __bf16 *wct, *whh_ct, *wih_gn, *whh_gn, *w_um, *w_uv, *w_f;
  const float  *bih_ct, *bhh_ct, *bih_gn, *bhh_gn, *b_um, *b_uv, *b_f;
  const __bf16* gihT;   // [200][384][512]
  const float*  g0;     // [512][256]
  const float*  epsT;   // [200][512][64]
  float *o_um, *o_ul, *o_f;
};
__global__ __launch_bounds__(512,1) void gen_scan(GenP P){
  const int tid=threadIdx.x, w=tid>>6, l=tid&63, lr=l&15, lq=l>>4;
  const int b0 = blockIdx.x*16;

  __shared__ __align__(16) __bf16 wgnL[768*64];      // 96KB wih_gn (resident)
  __shared__ __align__(16) __bf16 hcA[2][16*128];
  __shared__ __align__(16) __bf16 gA [2][16*256];
  __shared__ __align__(16) __bf16 uA [16*64];
  __shared__ __align__(16) __bf16 fA [16*64];

  for(int c=tid; c<6144; c+=512){
    int row = c>>3, part = c&7;
    bf16x8 v = *(const bf16x8*)(P.wih_gn + (size_t)row*64 + part*8);
    *(bf16x8*)((char*)wgnL + ((row*128 + part*16) ^ ((row&7)<<4))) = v;
  }
  // PINNED r,z gates of whh_gn (128 VGPRs); n-gate hoisted per step
  bf16x8 wrz[2][2][8];
  #pragma unroll
  for(int jt=0;jt<2;jt++)
    #pragma unroll
    for(int g=0;g<2;g++)
      #pragma unroll
      for(int kt=0;kt<8;kt++){
        wrz[jt][g][kt] = *(const bf16x8*)(P.whh_gn + (size_t)(g*256 + w*32 + jt*16 + lr)*256 + kt*32 + lq*8);
        pin8(wrz[jt][g][kt]);
      }

  const int dct = w*16 + lr;          // ctrl dim (all 8 waves)
  const int duu = (w&3)*16 + lr;      // u dims (waves 0-3) / f dims (waves 4-7)
  const float bctR = P.bih_ct[dct]     + P.bhh_ct[dct];
  const float bctZ = P.bih_ct[128+dct] + P.bhh_ct[128+dct];
  const float bctI = P.bih_ct[256+dct];
  const float bctH = P.bhh_ct[256+dct];
  float bgnR[2], bgnZ[2], bgnI[2], bgnH[2];
  #pragma unroll
  for(int jt=0;jt<2;jt++){
    int d = w*32 + jt*16 + lr;
    bgnR[jt] = P.bih_gn[d]     + P.bhh_gn[d];
    bgnZ[jt] = P.bih_gn[256+d] + P.bhh_gn[256+d];
    bgnI[jt] = P.bih_gn[512+d];
    bgnH[jt] = P.bhh_gn[512+d];
  }
  const float bum = P.b_um[duu], buv = P.b_uv[duu], bff = P.b_f[duu];

  // carries + init
  f32x4 gC[2], hcC;
  hcC = (f32x4){};
  #pragma unroll
  for(int jt=0;jt<2;jt++)
    #pragma unroll
    for(int rr=0;rr<4;rr++){
      float v = P.g0[(size_t)(b0+lq*4+rr)*256 + w*32 + jt*16 + lr];
      gC[jt][rr] = v;
      lds_wr(gA[0], lq*4+rr, w*32+jt*16+lr, 512, v);
    }
  for(int i=tid;i<16*128;i+=512) hcA[0][i] = (__bf16)0.f;
  __syncthreads();
  // f0 = g0 @ W_f^T + b_f (waves 4-7)
  if(w>=4){
    f32x4 fa={};
    #pragma unroll
    for(int kt=0;kt<8;kt++){
      bf16x8 gf = lds_rdA(gA[0], lr, kt, lq, 512);
      fa = MFMA_B16(gf, *(const bf16x8*)(P.w_f + (size_t)duu*256 + kt*32 + lq*8), fa);
    }
    #pragma unroll
    for(int rr=0;rr<4;rr++) lds_wr(fA, lq*4+rr, duu, 128, fa[rr]+bff);
  }
  // prefetch gihT(0) + eps(0)
  ushort4 gpR, gpZ, gpN; float epf[4];
  gpR = *(const ushort4*)(P.gihT + ((size_t)0*384 +       dct)*512 + b0 + lq*4);
  gpZ = *(const ushort4*)(P.gihT + ((size_t)0*384 + 128 + dct)*512 + b0 + lq*4);
  gpN = *(const ushort4*)(P.gihT + ((size_t)0*384 + 256 + dct)*512 + b0 + lq*4);
  if(w<4){
    #pragma unroll
    for(int rr=0;rr<4;rr++) epf[rr] = P.epsT[((size_t)0*512 + b0+lq*4+rr)*64 + duu];
  }
  // pre-load ctrl weights for t=0 (h-part + f-cols), refreshed each P4
  bf16x8 cwh[3][4], wctf[3][2];
  #pragma unroll
  for(int g=0;g<3;g++){
    #pragma unroll
    for(int kt=0;kt<4;kt++)
      cwh[g][kt] = *(const bf16x8*)(P.whh_ct + (size_t)(g*128+dct)*128 + kt*32 + lq*8);
    wctf[g][0] = *(const bf16x8*)(P.wct + (size_t)(g*128+dct)*576 + 512 + lq*8);
    wctf[g][1] = *(const bf16x8*)(P.wct + (size_t)(g*128+dct)*576 + 512 + 32 + lq*8);
  }
  __syncthreads();

  int pc=0, pg=0;
  #pragma unroll 1
  for(int t=0;t<TT;t++){
    // ---------- P1: controller GRU ----------
    bf16x8 wmv[8];                    // hoist um/uv weights for P2 (waves 0-3)
    if(w<4){
      const __bf16* wm = P.w_um + (size_t)duu*128 + lq*8;
      const __bf16* wv = P.w_uv + (size_t)duu*128 + lq*8;
      #pragma unroll
      for(int kt=0;kt<4;kt++){
        wmv[kt]   = *(const bf16x8*)(wm + kt*32);
        wmv[4+kt] = *(const bf16x8*)(wv + kt*32);
      }
    }
    {
      bf16x8 ff0 = lds_rdA(fA, lr, 0, lq, 128);
      bf16x8 ff1 = lds_rdA(fA, lr, 1, lq, 128);
      bf16x8 hp0 = lds_rdA(hcA[pc], lr, 0, lq, 256);
      bf16x8 hp1 = lds_rdA(hcA[pc], lr, 1, lq, 256);
      bf16x8 hp2 = lds_rdA(hcA[pc], lr, 2, lq, 256);
      bf16x8 hp3 = lds_rdA(hcA[pc], lr, 3, lq, 256);
      f32x4 aR={}, aZ={}, aI={}, aH={};
      aR = MFMA_B16(ff0,wctf[0][0],aR); aR = MFMA_B16(ff1,wctf[0][1],aR);
      aR = MFMA_B16(hp0,cwh[0][0],aR);  aR = MFMA_B16(hp1,cwh[0][1],aR);
      aR = MFMA_B16(hp2,cwh[0][2],aR);  aR = MFMA_B16(hp3,cwh[0][3],aR);
      aZ = MFMA_B16(ff0,wctf[1][0],aZ); aZ = MFMA_B16(ff1,wctf[1][1],aZ);
      aZ = MFMA_B16(hp0,cwh[1][0],aZ);  aZ = MFMA_B16(hp1,cwh[1][1],aZ);
      aZ = MFMA_B16(hp2,cwh[1][2],aZ);  aZ = MFMA_B16(hp3,cwh[1][3],aZ);
      aI = MFMA_B16(ff0,wctf[2][0],aI); aI = MFMA_B16(ff1,wctf[2][1],aI);
      aH = MFMA_B16(hp0,cwh[2][0],aH);  aH = MFMA_B16(hp1,cwh[2][1],aH);
      aH = MFMA_B16(hp2,cwh[2][2],aH);  aH = MFMA_B16(hp3,cwh[2][3],aH);
      const unsigned short* uR=(const unsigned short*)&gpR;
      const unsigned short* uZ=(const unsigned short*)&gpZ;
      const unsigned short* uN=(const unsigned short*)&gpN;
      #pragma unroll
      for(int rr=0;rr<4;rr++){
        float r = sig_f(aR[rr] + bf2f(uR[rr]) + bctR);
        float z = sig_f(aZ[rr] + bf2f(uZ[rr]) + bctZ);
        float nn= tanh_f(aI[rr] + bf2f(uN[rr]) + bctI + r*(aH[rr] + bctH));
        float h = (1.f-z)*nn + z*hcC[rr];
        h = fminf(fmaxf(h,0.f), 5.f);
        hcC[rr] = h;
        lds_wr(hcA[1-pc], lq*4+rr, dct, 256, h);
      }
    }
    lds_barrier();

    // ---------- P2: hoist n-gate weights (all waves), um/uv (waves 0-3) ----
    bf16x8 wnh[2][8];
    #pragma unroll
    for(int jt=0;jt<2;jt++)
      #pragma unroll
      for(int kt=0;kt<8;kt++)
        wnh[jt][kt] = *(const bf16x8*)(P.whh_gn + (size_t)(512 + w*32 + jt*16 + lr)*256 + kt*32 + lq*8);
    if(w<4){
      bf16x8 hn0 = lds_rdA(hcA[1-pc], lr, 0, lq, 256);
      bf16x8 hn1 = lds_rdA(hcA[1-pc], lr, 1, lq, 256);
      bf16x8 hn2 = lds_rdA(hcA[1-pc], lr, 2, lq, 256);
      bf16x8 hn3 = lds_rdA(hcA[1-pc], lr, 3, lq, 256);
      f32x4 am={}, av={};
      am = MFMA_B16(hn0, wmv[0], am);
      am = MFMA_B16(hn1, wmv[1], am);
      am = MFMA_B16(hn2, wmv[2], am);
      am = MFMA_B16(hn3, wmv[3], am);
      av = MFMA_B16(hn0, wmv[4], av);
      av = MFMA_B16(hn1, wmv[5], av);
      av = MFMA_B16(hn2, wmv[6], av);
      av = MFMA_B16(hn3, wmv[7], av);
      #pragma unroll
      for(int rr=0;rr<4;rr++){
        const int row = lq*4+rr;
        float um = am[rr] + bum;
        float ul = av[rr] + buv;
        size_t oi = ((size_t)(b0+row)*TT + t)*64 + duu;
        P.o_um[oi] = um;
        P.o_ul[oi] = ul;
        float u = epf[rr]*__expf(0.5f*ul) + um;
        lds_wr(uA, row, duu, 128, u);
      }
    }
    lds_barrier();

    // ---------- P3: generator GRU ----------
    bf16x8 wfh[8];                    // hoist w_f for P4 (waves 4-7)
    {
      const int tn = (t+1<TT)? t+1 : TT-1;
      gpR = *(const ushort4*)(P.gihT + ((size_t)tn*384 +       dct)*512 + b0 + lq*4);
      gpZ = *(const ushort4*)(P.gihT + ((size_t)tn*384 + 128 + dct)*512 + b0 + lq*4);
      gpN = *(const ushort4*)(P.gihT + ((size_t)tn*384 + 256 + dct)*512 + b0 + lq*4);
      if(w<4){
        #pragma unroll
        for(int rr=0;rr<4;rr++) epf[rr] = P.epsT[((size_t)tn*512 + b0+lq*4+rr)*64 + duu];
      }
      bf16x8 uf0 = lds_rdA(uA, lr, 0, lq, 128);
      bf16x8 uf1 = lds_rdA(uA, lr, 1, lq, 128);
      #pragma unroll
      for(int jt=0;jt<2;jt++){
        const int dg = w*32 + jt*16 + lr;
        f32x4 aR={}, aZ={}, aI={}, aH={};
        #pragma unroll
        for(int g=0;g<3;g++){
          const int row = g*256 + dg;
          bf16x8 w0 = *(const bf16x8*)((const char*)wgnL + ((row*128 +  0 + lq*16) ^ ((row&7)<<4)));
          bf16x8 w1 = *(const bf16x8*)((const char*)wgnL + ((row*128 + 64 + lq*16) ^ ((row&7)<<4)));
          if(g==0){ aR = MFMA_B16(uf0,w0,aR); aR = MFMA_B16(uf1,w1,aR); }
          else if(g==1){ aZ = MFMA_B16(uf0,w0,aZ); aZ = MFMA_B16(uf1,w1,aZ); }
          else { aI = MFMA_B16(uf0,w0,aI); aI = MFMA_B16(uf1,w1,aI); }
        }
        #pragma unroll
        for(int kt=0;kt<8;kt++){
          bf16x8 gf = lds_rdA(gA[pg], lr, kt, lq, 512);
          aR = MFMA_B16(gf, wrz[jt][0][kt], aR);
          aZ = MFMA_B16(gf, wrz[jt][1][kt], aZ);
          aH = MFMA_B16(gf, wnh[jt][kt], aH);
        }
        if(jt==0 && w>=4){            // wn[0] dead now: issue w_f loads
          const __bf16* wfp = P.w_f + (size_t)duu*256 + lq*8;
          #pragma unroll
          for(int kt=0;kt<8;kt++) wfh[kt] = *(const bf16x8*)(wfp + kt*32);
        }
        #pragma unroll
        for(int rr=0;rr<4;rr++){
          float r = sig_f(aR[rr] + bgnR[jt]);
          float z = sig_f(aZ[rr] + bgnZ[jt]);
          float nn= tanh_f(aI[rr] + bgnI[jt] + r*(aH[rr] + bgnH[jt]));
          float gv = (1.f-z)*nn + z*gC[jt][rr];
          gv = fminf(fmaxf(gv,0.f), 5.f);
          gC[jt][rr] = gv;
          lds_wr(gA[1-pg], lq*4+rr, dg, 512, gv);
        }
      }
    }
    lds_barrier();

    // ---------- P4: f = g @ W_f^T + b_f (waves 4-7) ----------
    if(w>=4){
      f32x4 fa={};
      #pragma unroll
      for(int kt=0;kt<8;kt++){
        bf16x8 gf = lds_rdA(gA[1-pg], lr, kt, lq, 512);
        fa = MFMA_B16(gf, wfh[kt], fa);
      }
      #pragma unroll
      for(int rr=0;rr<4;rr++){
        const int row = lq*4+rr;
        float v = fa[rr] + bff;
        P.o_f[((size_t)(b0+row)*TT + t)*64 + duu] = v;
        lds_wr(fA, row, duu, 128, v);
      }
    }
    // hoist ctrl weights for next P1 (h-part + f-cols)
    #pragma unroll
    for(int g=0;g<3;g++){
      #pragma unroll
      for(int kt=0;kt<4;kt++)
        cwh[g][kt] = *(const bf16x8*)(P.whh_ct + (size_t)(g*128+dct)*128 + kt*32 + lq*8);
      wctf[g][0] = *(const bf16x8*)(P.wct + (size_t)(g*128+dct)*576 + 512 + lq*8);
      wctf[g][1] = *(const bf16x8*)(P.wct + (size_t)(g*128+dct)*576 + 512 + 32 + lq*8);
    }
    lds_barrier();
    pc ^= 1; pg ^= 1;
  }
}

// ---------------- K6: rates ----------------
__global__ void rates_k(const float* __restrict__ fac, const float* __restrict__ Wr,
                        const float* __restrict__ br, float* __restrict__ out){
  const int total = 512*200*256;
  int i = blockIdx.x*blockDim.x + threadIdx.x;
  int st = gridDim.x*blockDim.x;
  for(; i<total; i+=st){
    int row = i>>8, n = i&255;
    const float4* fp=(const float4*)(fac + (size_t)row*64);
    const float4* wp=(const float4*)(Wr  + (size_t)n*64);
    float a = 0.f;
    #pragma unroll
    for(int k=0;k<16;k++){
      float4 f=fp[k], ww=wp[k];
      a += f.x*ww.x + f.y*ww.y + f.z*ww.z + f.w*ww.w;
    }
    a += br[n];
    a = fminf(fmaxf(a, -5.f), 5.f);
    out[i] = __expf(a);
  }
}

// ---------------- host ----------------
extern "C" void kernel_launch(void* const* d_in, const int* in_sizes, int n_in,
                              void* d_out, int out_size, void* d_ws, size_t ws_size,
                              hipStream_t stream){
  (void)in_sizes; (void)n_in; (void)out_size; (void)ws_size;
  const float* x      = (const float*)d_in[0];
  const float* eps_g0 = (const float*)d_in[1];
  const float* eps_u  = (const float*)d_in[2];
  const float* Wih_f[6]; const float* Whh_f[6]; const float* bih[6]; const float* bhh[6];
  for(int c=0;c<6;c++){
    Wih_f[c]=(const float*)d_in[3+4*c]; Whh_f[c]=(const float*)d_in[4+4*c];
    bih[c]  =(const float*)d_in[5+4*c]; bhh[c]  =(const float*)d_in[6+4*c];
  }
  const float* W_g0m=(const float*)d_in[27]; const float* b_g0m=(const float*)d_in[28];
  const float* W_g0v=(const float*)d_in[29]; const float* b_g0v=(const float*)d_in[30];
  const float* W_um =(const float*)d_in[31]; const float* b_um =(const float*)d_in[32];
  const float* W_uv =(const float*)d_in[33]; const float* b_uv =(const float*)d_in[34];
  const float* W_f  =(const float*)d_in[35]; const float* b_f  =(const float*)d_in[36];
  const float* W_r  =(const float*)d_in[37]; const float* b_r  =(const float*)d_in[38];

  char* ws = (char*)d_ws; size_t off = 0;
  auto alloc = [&](size_t bytes)->char*{
    char* p = ws + off; off = (off + bytes + 255) & ~(size_t)255; return p;
  };
  __bf16* wencall = (__bf16*)alloc((size_t)4*768*256*2);
  __bf16* whhall  = (__bf16*)alloc((size_t)4*768*256*2);
  __bf16* wct_b   = (__bf16*)alloc((size_t)384*576*2);
  __bf16* whhct_b = (__bf16*)alloc((size_t)384*128*2);
  __bf16* wihgn_b = (__bf16*)alloc((size_t)768*64*2);
  __bf16* whhgn_b = (__bf16*)alloc((size_t)768*256*2);
  __bf16* wum_b   = (__bf16*)alloc((size_t)64*128*2);
  __bf16* wuv_b   = (__bf16*)alloc((size_t)64*128*2);
  __bf16* wf_b    = (__bf16*)alloc((size_t)64*256*2);
  __bf16* henc    = (__bf16*)alloc((size_t)200*512*512*2);   // reused as epsT after gict
  __bf16* gi_buf  = (__bf16*)alloc((size_t)4*TC*768*512*2);  // reused as gictT
  float*  hcar    = (float*)alloc((size_t)4*512*256*4);
  float*  g0buf   = (float*)alloc((size_t)512*256*4);

  for(int c=0;c<4;c++){
    cvt_bf16<<<128,256,0,stream>>>(Wih_f[c], wencall + (size_t)c*768*256, 768*256);
    cvt_bf16<<<128,256,0,stream>>>(Whh_f[c], whhall  + (size_t)c*768*256, 768*256);
  }
  cvt_bf16<<<128,256,0,stream>>>(Wih_f[4], wct_b,   384*576);
  cvt_bf16<<<64 ,256,0,stream>>>(Whh_f[4], whhct_b, 384*128);
  cvt_bf16<<<64 ,256,0,stream>>>(Wih_f[5], wihgn_b, 768*64);
  cvt_bf16<<<128,256,0,stream>>>(Whh_f[5], whhgn_b, 768*256);
  cvt_bf16<<<32 ,256,0,stream>>>(W_um, wum_b, 64*128);
  cvt_bf16<<<32 ,256,0,stream>>>(W_uv, wuv_b, 64*128);
  cvt_bf16<<<32 ,256,0,stream>>>(W_f,  wf_b,  64*256);
  hipMemsetAsync(hcar, 0, (size_t)4*512*256*4, stream);

  EncP ep;
  ep.whh = whhall;
  for(int c=0;c<4;c++){ ep.bih[c]=bih[c]; ep.bhh[c]=bhh[c]; }
  ep.gi = gi_buf; ep.henc = henc; ep.hcar = hcar;
  for(int k=0;k<NCH;k++){
    gi_gemm<<<dim3((512*TC)/64,4),256,0,stream>>>(x, wencall, gi_buf, k*TC);
    ep.t0 = k*TC;
    enc_scan<<<dim3(32,4),512,0,stream>>>(ep);
  }

  float* out = (float*)d_out;
  float* o_mean = out;
  float* o_logv = out + 131072;
  float* o_um   = out + 262144;
  float* o_ul   = out + 6815744;
  float* o_f    = out + 13369344;
  float* o_r    = out + 19922944;

  g0_kernel<<<512,256,0,stream>>>(hcar + 0, hcar + (size_t)1*512*256,
                                  W_g0m,b_g0m, W_g0v,b_g0v, eps_g0,
                                  o_mean,o_logv, g0buf);
  gict_gemm<<<800,256,0,stream>>>(henc, wct_b, gi_buf);

  // henc is dead after gict_gemm: reuse its space for the eps transpose
  float* epsT = (float*)henc;
  epsT_k<<<2048,256,0,stream>>>((const float4*)eps_u, (float4*)epsT);

  GenP gp;
  gp.wct=wct_b; gp.whh_ct=whhct_b; gp.wih_gn=wihgn_b; gp.whh_gn=whhgn_b;
  gp.w_um=wum_b; gp.w_uv=wuv_b; gp.w_f=wf_b;
  gp.bih_ct=bih[4]; gp.bhh_ct=bhh[4]; gp.bih_gn=bih[5]; gp.bhh_gn=bhh[5];
  gp.b_um=b_um; gp.b_uv=b_uv; gp.b_f=b_f;
  gp.gihT=gi_buf; gp.g0=g0buf; gp.epsT=epsT;
  gp.o_um=o_um; gp.o_ul=o_ul; gp.o_f=o_f;
  gen_scan<<<32,512,0,stream>>>(gp);

  rates_k<<<8192,256,0,stream>>>(o_f, W_r, b_r, o_r);
}

// Round 6
// 7336.761 us; speedup vs baseline: 1.1532x; 1.1532x over previous
//
#include <hip/hip_runtime.h>
#include <hip/hip_bf16.h>
#include <stdint.h>

typedef __bf16 bf16x8 __attribute__((ext_vector_type(8)));
typedef __bf16 bf16x4 __attribute__((ext_vector_type(4)));
typedef float  f32x4  __attribute__((ext_vector_type(4)));
typedef unsigned short u16x8 __attribute__((ext_vector_type(8)));

#define MFMA_B16(A_,B_,C_) __builtin_amdgcn_mfma_f32_16x16x32_bf16((A_),(B_),(C_),0,0,0)

static constexpr int TT = 200;
static constexpr int TC = 25;     // T-chunk for encoder
static constexpr int NCH = 8;     // chunks

static __device__ __forceinline__ float sig_f(float x){ return 1.f/(1.f+__expf(-x)); }
static __device__ __forceinline__ float tanh_f(float x){
  float e = __expf(-2.f*fabsf(x));
  float t = (1.f-e)/(1.f+e);
  return x<0.f ? -t : t;
}
static __device__ __forceinline__ float bf2f(unsigned short u){
  union{unsigned int i; float f;} v; v.i = ((unsigned)u)<<16; return v.f;
}
static __device__ __forceinline__ void pin8(bf16x8 &v){ asm volatile("" : "+v"(v)); }

// swizzled LDS helpers (row-major tile, byte ^= (row&7)<<4)
static __device__ __forceinline__ int swz_off(int row, int col_bytes, int strideB){
  return (row*strideB + col_bytes) ^ ((row&7)<<4);
}
static __device__ __forceinline__ bf16x8 lds_rdA(const __bf16* buf, int row, int kt, int lq, int strideB){
  return *(const bf16x8*)((const char*)buf + swz_off(row, kt*64 + lq*16, strideB));
}
static __device__ __forceinline__ void lds_wr(__bf16* buf, int row, int dim, int strideB, float v){
  *(__bf16*)((char*)buf + swz_off(row, dim*2, strideB)) = (__bf16)v;
}
// lgkm-only barrier: keeps global loads in flight across the barrier
static __device__ __forceinline__ void lds_barrier(){
  asm volatile("s_waitcnt lgkmcnt(0)" ::: "memory");
  __builtin_amdgcn_s_barrier();
}

// ---------------- K0: f32 -> bf16 ----------------
__global__ void cvt_bf16(const float* __restrict__ s, __bf16* __restrict__ d, int n){
  int i = blockIdx.x*blockDim.x + threadIdx.x;
  int st = gridDim.x*blockDim.x;
  for(; i<n; i+=st) d[i] = (__bf16)s[i];
}

// ---------------- K0b: eps transpose [512][200][64] -> [200][512][64] ------
__global__ void epsT_k(const float4* __restrict__ e, float4* __restrict__ o){
  const int total = 512*200*16;
  int j = blockIdx.x*blockDim.x + threadIdx.x;
  int st = gridDim.x*blockDim.x;
  for(; j<total; j+=st){
    int b = j/3200, rem = j - b*3200;
    int t = rem>>4, dq = rem&15;
    o[((size_t)t*512 + b)*16 + dq] = e[j];
  }
}

// ---------------- K1: gi GEMM (per chunk) ----------------
__global__ __launch_bounds__(256) void gi_gemm(const float* __restrict__ x,
                                               const __bf16* __restrict__ Wall, // [4*768][256]
                                               __bf16* __restrict__ gi, int t0){
  const int tid=threadIdx.x, w=tid>>6, l=tid&63, lr=l&15, lq=l>>4;
  const int cell = blockIdx.y;
  const bool fwd = (cell&1)==0;
  const int m0 = blockIdx.x*64;
  const int tloc = m0>>9, b0 = m0&511;
  const int tabs = fwd ? (t0+tloc) : (TT-1-(t0+tloc));
  const int brow = b0 + w*16 + lr;

  const float* xp = x + (size_t)brow*TT*256 + (size_t)tabs*256 + lq*8;
  bf16x8 a[8];
  #pragma unroll
  for(int kt=0;kt<8;kt++){
    float4 f0 = *(const float4*)(xp + kt*32);
    float4 f1 = *(const float4*)(xp + kt*32 + 4);
    bf16x8 v;
    v[0]=(__bf16)f0.x; v[1]=(__bf16)f0.y; v[2]=(__bf16)f0.z; v[3]=(__bf16)f0.w;
    v[4]=(__bf16)f1.x; v[5]=(__bf16)f1.y; v[6]=(__bf16)f1.z; v[7]=(__bf16)f1.w;
    a[kt]=v;
  }
  const __bf16* Wc = Wall + (size_t)cell*768*256;
  #pragma unroll 1
  for(int nt=0;nt<48;nt++){
    f32x4 acc={};
    const __bf16* bp = Wc + (size_t)(nt*16+lr)*256 + lq*8;
    #pragma unroll
    for(int kt=0;kt<8;kt++)
      acc = MFMA_B16(a[kt], *(const bf16x8*)(bp + kt*32), acc);
    bf16x4 pk;
    pk[0]=(__bf16)acc[0]; pk[1]=(__bf16)acc[1]; pk[2]=(__bf16)acc[2]; pk[3]=(__bf16)acc[3];
    *(bf16x4*)(gi + (((size_t)cell*TC + tloc)*768 + nt*16+lr)*512 + b0 + w*16 + lq*4) = pk;
  }
}

// ---------------- K2: encoder scan (r,z PINNED; waves_per_eu(2,2)) ---------
struct EncP{
  const __bf16* whh;            // [4][768][256]
  const float*  bih[4];
  const float*  bhh[4];
  const __bf16* gi;             // [4][TC][768][512]
  __bf16* henc;                 // [200][512][512]
  float*  hcar;                 // [4][512][256]
  int t0;
};
__attribute__((amdgpu_waves_per_eu(2,2)))
__global__ __launch_bounds__(512) void enc_scan(EncP P){
  const int tid=threadIdx.x, w=tid>>6, l=tid&63, lr=l&15, lq=l>>4;
  const int cell=blockIdx.y, b0=blockIdx.x*16;
  const bool fwd = (cell&1)==0;
  const bool isC = cell>=2;
  const int dim0 = w*32;

  __shared__ __align__(16) __bf16 hA[2][16*256];     // 2 x 8KB
  __shared__ __align__(16) __bf16 giL[2][768*16];    // 2 x 24KB
  __shared__ float blds[1024];

  for(int d=tid; d<256; d+=512){
    blds[d]     = P.bih[cell][d]     + P.bhh[cell][d];
    blds[256+d] = P.bih[cell][256+d] + P.bhh[cell][256+d];
    blds[512+d] = P.bih[cell][512+d];
    blds[768+d] = P.bhh[cell][512+d];
  }
  const __bf16* Wh = P.whh + (size_t)cell*768*256;
  // PINNED r,z gate weights (128 VGPRs); n-gate streamed JIT each step
  bf16x8 wreg[2][2][8];
  #pragma unroll
  for(int jt=0;jt<2;jt++)
    #pragma unroll
    for(int g=0;g<2;g++)
      #pragma unroll
      for(int kt=0;kt<8;kt++){
        wreg[jt][g][kt] = *(const bf16x8*)(Wh + (size_t)(g*256 + dim0 + jt*16 + lr)*256 + kt*32 + lq*8);
        pin8(wreg[jt][g][kt]);
      }
  // carry
  f32x4 hold[2];
  #pragma unroll
  for(int jt=0;jt<2;jt++)
    #pragma unroll
    for(int rr=0;rr<4;rr++){
      float v = P.hcar[((size_t)cell*512 + b0 + lq*4+rr)*256 + dim0 + jt*16 + lr];
      hold[jt][rr] = v;
      lds_wr(hA[0], lq*4+rr, dim0+jt*16+lr, 512, v);
    }
  // gi staging: wave w stages gate-rows [w*96, w*96+96)
  const int prow = w*96 + (l>>1), phal = l&1;
  const __bf16* gbase = P.gi + ((size_t)cell*TC*768 + prow)*512 + b0 + phal*8;
  u16x8 pf0, pf1, pf2;
  pf0 = *(const u16x8*)(gbase + (size_t)0*768*512 +  0*512);
  pf1 = *(const u16x8*)(gbase + (size_t)0*768*512 + 32*512);
  pf2 = *(const u16x8*)(gbase + (size_t)0*768*512 + 64*512);
  __syncthreads();
  {
    __bf16* gl = giL[0] + prow*16 + phal*8;
    *(u16x8*)(gl)        = pf0;
    *(u16x8*)(gl+32*16)  = pf1;
    *(u16x8*)(gl+64*16)  = pf2;
  }
  { int sn = 1 < TC ? 1 : TC-1;
    pf0 = *(const u16x8*)(gbase + (size_t)sn*768*512 +  0*512);
    pf1 = *(const u16x8*)(gbase + (size_t)sn*768*512 + 32*512);
    pf2 = *(const u16x8*)(gbase + (size_t)sn*768*512 + 64*512);
  }
  lds_barrier();

  int p=0, q=0;
  #pragma unroll 1
  for(int s=0;s<TC;s++){
    const int tglob = P.t0 + s;
    const int tx = fwd ? tglob : (TT-1-tglob);
    if(s+1<TC){
      __bf16* gl = giL[1-q] + prow*16 + phal*8;
      *(u16x8*)(gl)        = pf0;
      *(u16x8*)(gl+32*16)  = pf1;
      *(u16x8*)(gl+64*16)  = pf2;
    }
    { int sn = (s+2<TC) ? s+2 : TC-1;
      pf0 = *(const u16x8*)(gbase + (size_t)sn*768*512 +  0*512);
      pf1 = *(const u16x8*)(gbase + (size_t)sn*768*512 + 32*512);
      pf2 = *(const u16x8*)(gbase + (size_t)sn*768*512 + 64*512);
    }
    const __bf16* gq = giL[q];
    #pragma unroll
    for(int jt=0;jt<2;jt++){
      const int d = dim0 + jt*16 + lr;
      const __bf16* whN = Wh + (size_t)(512 + d)*256 + lq*8;   // n-gate JIT
      f32x4 aR={}, aZ={}, aH={};
      #pragma unroll
      for(int kt=0;kt<8;kt++){
        bf16x8 frag = lds_rdA(hA[p], lr, kt, lq, 512);
        aR = MFMA_B16(frag, wreg[jt][0][kt], aR);
        aZ = MFMA_B16(frag, wreg[jt][1][kt], aZ);
        aH = MFMA_B16(frag, *(const bf16x8*)(whN + kt*32), aH);
      }
      ushort4 gR = *(const ushort4*)(gq + (0*256+d)*16 + lq*4);
      ushort4 gZ = *(const ushort4*)(gq + (1*256+d)*16 + lq*4);
      ushort4 gN = *(const ushort4*)(gq + (2*256+d)*16 + lq*4);
      const float bR=blds[d], bZ=blds[256+d], bI=blds[512+d], bH=blds[768+d];
      const unsigned short* uR=(const unsigned short*)&gR;
      const unsigned short* uZ=(const unsigned short*)&gZ;
      const unsigned short* uN=(const unsigned short*)&gN;
      #pragma unroll
      for(int rr=0;rr<4;rr++){
        float r = sig_f(aR[rr] + bf2f(uR[rr]) + bR);
        float z = sig_f(aZ[rr] + bf2f(uZ[rr]) + bZ);
        float nn= tanh_f(bf2f(uN[rr]) + bI + r*(aH[rr] + bH));
        float h = (1.f-z)*nn + z*hold[jt][rr];
        h = fminf(h, 5.f);
        hold[jt][rr] = h;
        lds_wr(hA[1-p], lq*4+rr, d, 512, h);
      }
    }
    if(isC){
      const int row = l>>2, dgrp = (l&3)*8;
      bf16x8 hv = *(const bf16x8*)((const char*)hA[1-p] +
                    ((row*512 + (dim0+dgrp)*2) ^ ((row&7)<<4)));
      *(bf16x8*)(P.henc + ((size_t)tx*512 + b0 + row)*512 + (cell==3?256:0) + dim0 + dgrp) = hv;
    }
    lds_barrier();
    p ^= 1; q ^= 1;
  }
  #pragma unroll
  for(int jt=0;jt<2;jt++)
    #pragma unroll
    for(int rr=0;rr<4;rr++)
      P.hcar[((size_t)cell*512 + b0 + lq*4+rr)*256 + dim0 + jt*16 + lr] = hold[jt][rr];
}

// ---------------- K3: g0 head ----------------
__global__ void g0_kernel(const float* __restrict__ hgf, const float* __restrict__ hgb,
                          const float* __restrict__ Wm, const float* __restrict__ bm,
                          const float* __restrict__ Wv, const float* __restrict__ bv,
                          const float* __restrict__ eps,
                          float* __restrict__ o_mean, float* __restrict__ o_logv,
                          float* __restrict__ g0){
  int j = blockIdx.x*blockDim.x + threadIdx.x;    // 512*256
  int b = j>>8, d = j&255;
  const float4* hf=(const float4*)(hgf + (size_t)b*256);
  const float4* hb=(const float4*)(hgb + (size_t)b*256);
  const float4* mp=(const float4*)(Wm + (size_t)d*512);
  const float4* vp=(const float4*)(Wv + (size_t)d*512);
  float am=0.f, av=0.f;
  #pragma unroll 4
  for(int k=0;k<64;k++){
    float4 h=hf[k], m=mp[k], v=vp[k];
    am += h.x*m.x + h.y*m.y + h.z*m.z + h.w*m.w;
    av += h.x*v.x + h.y*v.y + h.z*v.z + h.w*v.w;
  }
  #pragma unroll 4
  for(int k=0;k<64;k++){
    float4 h=hb[k], m=mp[64+k], v=vp[64+k];
    am += h.x*m.x + h.y*m.y + h.z*m.z + h.w*m.w;
    av += h.x*v.x + h.y*v.y + h.z*v.z + h.w*v.w;
  }
  float mean = am + bm[d];
  float ev   = __expf(av + bv[d]) + 1e-4f;
  float lv   = __logf(ev);
  o_mean[j]=mean; o_logv[j]=lv;
  g0[j] = eps[j]*sqrtf(ev) + mean;
}

// ---------------- K4: gictT[t][384][512] ----------------
__global__ __launch_bounds__(256,2) void gict_gemm(const __bf16* __restrict__ henc,
                                                   const __bf16* __restrict__ wct,   // [384][576]
                                                   __bf16* __restrict__ gictT){
  const int tid=threadIdx.x, w=tid>>6, l=tid&63, lr=l&15, lq=l>>4;
  const int m0 = blockIdx.x*8 + w*2;
  bf16x8 a[2][16];
  #pragma unroll
  for(int m=0;m<2;m++){
    const __bf16* ap = henc + (size_t)((m0+m)*16 + lr)*512 + lq*8;
    #pragma unroll
    for(int kt=0;kt<16;kt++) a[m][kt] = *(const bf16x8*)(ap + kt*32);
  }
  #pragma unroll 1
  for(int nt=0;nt<24;nt++){
    f32x4 c0={}, c1={};
    const __bf16* bp = wct + (size_t)(nt*16+lr)*576 + lq*8;
    #pragma unroll
    for(int kt=0;kt<16;kt++){
      bf16x8 bb = *(const bf16x8*)(bp + kt*32);
      c0 = MFMA_B16(a[0][kt], bb, c0);
      c1 = MFMA_B16(a[1][kt], bb, c1);
    }
    #pragma unroll
    for(int m=0;m<2;m++){
      f32x4 c = m? c1 : c0;
      int R0 = (m0+m)*16 + lq*4;
      int t  = R0>>9, b = R0&511;
      bf16x4 pk;
      pk[0]=(__bf16)c[0]; pk[1]=(__bf16)c[1]; pk[2]=(__bf16)c[2]; pk[3]=(__bf16)c[3];
      *(bf16x4*)(gictT + ((size_t)t*384 + nt*16+lr)*512 + b) = pk;
    }
  }
}

// ---------------- K5: generator scan (R3 structure + pinned wrz) ----------
struct GenP{
  const __bf16 *wct, *whh_ct, *wih_gn, *whh_gn, *w_um, *w_uv, *w_f;
  const float  *bih_ct, *bhh_ct, *bih_gn, *bhh_gn, *b_um, *b_uv, *b_f;
  const __bf16* gihT;   // [200][384][512]
  const float*  g0;     // [512][256]
  const float*  epsT;   // [200][512][64]
  float *o_um, *o_ul, *o_f;
};
__attribute__((amdgpu_waves_per_eu(2,2)))
__global__ __launch_bounds__(512) void gen_scan(GenP P){
  const int tid=threadIdx.x, w=tid>>6, l=tid&63, lr=l&15, lq=l>>4;
  const int b0 = blockIdx.x*16;

  __shared__ __align__(16) __bf16 wgnL[768*64];      // 96KB wih_gn (resident)
  __shared__ __align__(16) __bf16 hcA[2][16*128];
  __shared__ __align__(16) __bf16 gA [2][16*256];
  __shared__ __align__(16) __bf16 uA [16*64];
  __shared__ __align__(16) __bf16 fA [16*64];

  for(int c=tid; c<6144; c+=512){
    int row = c>>3, part = c&7;
    bf16x8 v = *(const bf16x8*)(P.wih_gn + (size_t)row*64 + part*8);
    *(bf16x8*)((char*)wgnL + ((row*128 + part*16) ^ ((row&7)<<4))) = v;
  }
  // PINNED r,z gates of whh_gn (128 VGPRs)
  bf16x8 wrz[2][2][8];
  #pragma unroll
  for(int jt=0;jt<2;jt++)
    #pragma unroll
    for(int g=0;g<2;g++)
      #pragma unroll
      for(int kt=0;kt<8;kt++){
        wrz[jt][g][kt] = *(const bf16x8*)(P.whh_gn + (size_t)(g*256 + w*32 + jt*16 + lr)*256 + kt*32 + lq*8);
        pin8(wrz[jt][g][kt]);
      }

  const int dct = w*16 + lr;          // ctrl dim (all 8 waves)
  const int duu = (w&3)*16 + lr;      // u dims (waves 0-3) / f dims (waves 4-7)
  const float bctR = P.bih_ct[dct]     + P.bhh_ct[dct];
  const float bctZ = P.bih_ct[128+dct] + P.bhh_ct[128+dct];
  const float bctI = P.bih_ct[256+dct];
  const float bctH = P.bhh_ct[256+dct];
  float bgnR[2], bgnZ[2], bgnI[2], bgnH[2];
  #pragma unroll
  for(int jt=0;jt<2;jt++){
    int d = w*32 + jt*16 + lr;
    bgnR[jt] = P.bih_gn[d]     + P.bhh_gn[d];
    bgnZ[jt] = P.bih_gn[256+d] + P.bhh_gn[256+d];
    bgnI[jt] = P.bih_gn[512+d];
    bgnH[jt] = P.bhh_gn[512+d];
  }
  const float bum = P.b_um[duu], buv = P.b_uv[duu], bff = P.b_f[duu];

  // carries + init
  f32x4 gC[2], hcC;
  hcC = (f32x4){};
  #pragma unroll
  for(int jt=0;jt<2;jt++)
    #pragma unroll
    for(int rr=0;rr<4;rr++){
      float v = P.g0[(size_t)(b0+lq*4+rr)*256 + w*32 + jt*16 + lr];
      gC[jt][rr] = v;
      lds_wr(gA[0], lq*4+rr, w*32+jt*16+lr, 512, v);
    }
  for(int i=tid;i<16*128;i+=512) hcA[0][i] = (__bf16)0.f;
  __syncthreads();
  // f0 = g0 @ W_f^T + b_f (waves 4-7)
  if(w>=4){
    f32x4 fa={};
    #pragma unroll
    for(int kt=0;kt<8;kt++){
      bf16x8 gf = lds_rdA(gA[0], lr, kt, lq, 512);
      fa = MFMA_B16(gf, *(const bf16x8*)(P.w_f + (size_t)duu*256 + kt*32 + lq*8), fa);
    }
    #pragma unroll
    for(int rr=0;rr<4;rr++) lds_wr(fA, lq*4+rr, duu, 128, fa[rr]+bff);
  }
  // prefetch gihT(0) + eps(0)
  ushort4 gpR, gpZ, gpN; float epf[4];
  gpR = *(const ushort4*)(P.gihT + ((size_t)0*384 +       dct)*512 + b0 + lq*4);
  gpZ = *(const ushort4*)(P.gihT + ((size_t)0*384 + 128 + dct)*512 + b0 + lq*4);
  gpN = *(const ushort4*)(P.gihT + ((size_t)0*384 + 256 + dct)*512 + b0 + lq*4);
  if(w<4){
    #pragma unroll
    for(int rr=0;rr<4;rr++) epf[rr] = P.epsT[((size_t)0*512 + b0+lq*4+rr)*64 + duu];
  }
  // pre-load ctrl h-weights for t=0 (refreshed each P4)
  bf16x8 cwh[3][4];
  #pragma unroll
  for(int g=0;g<3;g++)
    #pragma unroll
    for(int kt=0;kt<4;kt++)
      cwh[g][kt] = *(const bf16x8*)(P.whh_ct + (size_t)(g*128+dct)*128 + kt*32 + lq*8);
  __syncthreads();

  int pc=0, pg=0;
  #pragma unroll 1
  for(int t=0;t<TT;t++){
    // ---------- P1: controller GRU ----------
    {
      bf16x8 ff0 = lds_rdA(fA, lr, 0, lq, 128);
      bf16x8 ff1 = lds_rdA(fA, lr, 1, lq, 128);
      bf16x8 hp0 = lds_rdA(hcA[pc], lr, 0, lq, 256);
      bf16x8 hp1 = lds_rdA(hcA[pc], lr, 1, lq, 256);
      bf16x8 hp2 = lds_rdA(hcA[pc], lr, 2, lq, 256);
      bf16x8 hp3 = lds_rdA(hcA[pc], lr, 3, lq, 256);
      f32x4 aR={}, aZ={}, aI={}, aH={};
      #pragma unroll
      for(int g=0;g<3;g++){
        const __bf16* wif = P.wct + (size_t)(g*128+dct)*576 + 512 + lq*8;  // f-cols JIT
        bf16x8 wf0 = *(const bf16x8*)(wif);
        bf16x8 wf1 = *(const bf16x8*)(wif + 32);
        if(g==0){
          aR = MFMA_B16(ff0,wf0,aR); aR = MFMA_B16(ff1,wf1,aR);
          aR = MFMA_B16(hp0,cwh[0][0],aR); aR = MFMA_B16(hp1,cwh[0][1],aR);
          aR = MFMA_B16(hp2,cwh[0][2],aR); aR = MFMA_B16(hp3,cwh[0][3],aR);
        }else if(g==1){
          aZ = MFMA_B16(ff0,wf0,aZ); aZ = MFMA_B16(ff1,wf1,aZ);
          aZ = MFMA_B16(hp0,cwh[1][0],aZ); aZ = MFMA_B16(hp1,cwh[1][1],aZ);
          aZ = MFMA_B16(hp2,cwh[1][2],aZ); aZ = MFMA_B16(hp3,cwh[1][3],aZ);
        }else{
          aI = MFMA_B16(ff0,wf0,aI); aI = MFMA_B16(ff1,wf1,aI);
          aH = MFMA_B16(hp0,cwh[2][0],aH); aH = MFMA_B16(hp1,cwh[2][1],aH);
          aH = MFMA_B16(hp2,cwh[2][2],aH); aH = MFMA_B16(hp3,cwh[2][3],aH);
        }
      }
      const unsigned short* uR=(const unsigned short*)&gpR;
      const unsigned short* uZ=(const unsigned short*)&gpZ;
      const unsigned short* uN=(const unsigned short*)&gpN;
      #pragma unroll
      for(int rr=0;rr<4;rr++){
        float r = sig_f(aR[rr] + bf2f(uR[rr]) + bctR);
        float z = sig_f(aZ[rr] + bf2f(uZ[rr]) + bctZ);
        float nn= tanh_f(aI[rr] + bf2f(uN[rr]) + bctI + r*(aH[rr] + bctH));
        float h = (1.f-z)*nn + z*hcC[rr];
        h = fminf(fmaxf(h,0.f), 5.f);
        hcC[rr] = h;
        lds_wr(hcA[1-pc], lq*4+rr, dct, 256, h);
      }
    }
    lds_barrier();

    // ---------- P2: um/uv (waves 0-3); hoist n-gate jt=0 for P3 ----------
    if(w<4){
      bf16x8 hn0 = lds_rdA(hcA[1-pc], lr, 0, lq, 256);
      bf16x8 hn1 = lds_rdA(hcA[1-pc], lr, 1, lq, 256);
      bf16x8 hn2 = lds_rdA(hcA[1-pc], lr, 2, lq, 256);
      bf16x8 hn3 = lds_rdA(hcA[1-pc], lr, 3, lq, 256);
      f32x4 am={}, av={};
      const __bf16* wm = P.w_um + (size_t)duu*128 + lq*8;
      const __bf16* wv = P.w_uv + (size_t)duu*128 + lq*8;
      am = MFMA_B16(hn0, *(const bf16x8*)(wm   ), am);
      am = MFMA_B16(hn1, *(const bf16x8*)(wm+32), am);
      am = MFMA_B16(hn2, *(const bf16x8*)(wm+64), am);
      am = MFMA_B16(hn3, *(const bf16x8*)(wm+96), am);
      av = MFMA_B16(hn0, *(const bf16x8*)(wv   ), av);
      av = MFMA_B16(hn1, *(const bf16x8*)(wv+32), av);
      av = MFMA_B16(hn2, *(const bf16x8*)(wv+64), av);
      av = MFMA_B16(hn3, *(const bf16x8*)(wv+96), av);
      #pragma unroll
      for(int rr=0;rr<4;rr++){
        const int row = lq*4+rr;
        float um = am[rr] + bum;
        float ul = av[rr] + buv;
        size_t oi = ((size_t)(b0+row)*TT + t)*64 + duu;
        P.o_um[oi] = um;
        P.o_ul[oi] = ul;
        float u = epf[rr]*__expf(0.5f*ul) + um;
        lds_wr(uA, row, duu, 128, u);
      }
    }
    bf16x8 wn0[8];
    #pragma unroll
    for(int kt=0;kt<8;kt++)
      wn0[kt] = *(const bf16x8*)(P.whh_gn + (size_t)(512 + w*32 + lr)*256 + kt*32 + lq*8);
    lds_barrier();

    // ---------- P3: generator GRU ----------
    {
      const int tn = (t+1<TT)? t+1 : TT-1;
      gpR = *(const ushort4*)(P.gihT + ((size_t)tn*384 +       dct)*512 + b0 + lq*4);
      gpZ = *(const ushort4*)(P.gihT + ((size_t)tn*384 + 128 + dct)*512 + b0 + lq*4);
      gpN = *(const ushort4*)(P.gihT + ((size_t)tn*384 + 256 + dct)*512 + b0 + lq*4);
      if(w<4){
        #pragma unroll
        for(int rr=0;rr<4;rr++) epf[rr] = P.epsT[((size_t)tn*512 + b0+lq*4+rr)*64 + duu];
      }
      bf16x8 uf0 = lds_rdA(uA, lr, 0, lq, 128);
      bf16x8 uf1 = lds_rdA(uA, lr, 1, lq, 128);
      #pragma unroll
      for(int jt=0;jt<2;jt++){
        const int dg = w*32 + jt*16 + lr;
        bf16x8 wn[8];
        if(jt==0){
          #pragma unroll
          for(int kt=0;kt<8;kt++) wn[kt] = wn0[kt];
        }else{
          #pragma unroll
          for(int kt=0;kt<8;kt++)
            wn[kt] = *(const bf16x8*)(P.whh_gn + (size_t)(512 + dg)*256 + kt*32 + lq*8);
        }
        f32x4 aR={}, aZ={}, aI={}, aH={};
        #pragma unroll
        for(int g=0;g<3;g++){
          const int row = g*256 + dg;
          bf16x8 w0 = *(const bf16x8*)((const char*)wgnL + ((row*128 +  0 + lq*16) ^ ((row&7)<<4)));
          bf16x8 w1 = *(const bf16x8*)((const char*)wgnL + ((row*128 + 64 + lq*16) ^ ((row&7)<<4)));
          if(g==0){ aR = MFMA_B16(uf0,w0,aR); aR = MFMA_B16(uf1,w1,aR); }
          else if(g==1){ aZ = MFMA_B16(uf0,w0,aZ); aZ = MFMA_B16(uf1,w1,aZ); }
          else { aI = MFMA_B16(uf0,w0,aI); aI = MFMA_B16(uf1,w1,aI); }
        }
        #pragma unroll
        for(int kt=0;kt<8;kt++){
          bf16x8 gf = lds_rdA(gA[pg], lr, kt, lq, 512);
          aR = MFMA_B16(gf, wrz[jt][0][kt], aR);
          aZ = MFMA_B16(gf, wrz[jt][1][kt], aZ);
          aH = MFMA_B16(gf, wn[kt], aH);
        }
        #pragma unroll
        for(int rr=0;rr<4;rr++){
          float r = sig_f(aR[rr] + bgnR[jt]);
          float z = sig_f(aZ[rr] + bgnZ[jt]);
          float nn= tanh_f(aI[rr] + bgnI[jt] + r*(aH[rr] + bgnH[jt]));
          float gv = (1.f-z)*nn + z*gC[jt][rr];
          gv = fminf(fmaxf(gv,0.f), 5.f);
          gC[jt][rr] = gv;
          lds_wr(gA[1-pg], lq*4+rr, dg, 512, gv);
        }
      }
    }
    lds_barrier();

    // ---------- P4: f = g @ W_f^T + b_f (waves 4-7) ----------
    if(w>=4){
      f32x4 fa={};
      const __bf16* wfp = P.w_f + (size_t)duu*256 + lq*8;
      #pragma unroll
      for(int kt=0;kt<8;kt++){
        bf16x8 gf = lds_rdA(gA[1-pg], lr, kt, lq, 512);
        fa = MFMA_B16(gf, *(const bf16x8*)(wfp + kt*32), fa);
      }
      #pragma unroll
      for(int rr=0;rr<4;rr++){
        const int row = lq*4+rr;
        float v = fa[rr] + bff;
        P.o_f[((size_t)(b0+row)*TT + t)*64 + duu] = v;
        lds_wr(fA, row, duu, 128, v);
      }
    }
    // hoist ctrl h-weights for next P1
    #pragma unroll
    for(int g=0;g<3;g++)
      #pragma unroll
      for(int kt=0;kt<4;kt++)
        cwh[g][kt] = *(const bf16x8*)(P.whh_ct + (size_t)(g*128+dct)*128 + kt*32 + lq*8);
    lds_barrier();
    pc ^= 1; pg ^= 1;
  }
}

// ---------------- K6: rates ----------------
__global__ void rates_k(const float* __restrict__ fac, const float* __restrict__ Wr,
                        const float* __restrict__ br, float* __restrict__ out){
  const int total = 512*200*256;
  int i = blockIdx.x*blockDim.x + threadIdx.x;
  int st = gridDim.x*blockDim.x;
  for(; i<total; i+=st){
    int row = i>>8, n = i&255;
    const float4* fp=(const float4*)(fac + (size_t)row*64);
    const float4* wp=(const float4*)(Wr  + (size_t)n*64);
    float a = 0.f;
    #pragma unroll
    for(int k=0;k<16;k++){
      float4 f=fp[k], ww=wp[k];
      a += f.x*ww.x + f.y*ww.y + f.z*ww.z + f.w*ww.w;
    }
    a += br[n];
    a = fminf(fmaxf(a, -5.f), 5.f);
    out[i] = __expf(a);
  }
}

// ---------------- host ----------------
extern "C" void kernel_launch(void* const* d_in, const int* in_sizes, int n_in,
                              void* d_out, int out_size, void* d_ws, size_t ws_size,
                              hipStream_t stream){
  (void)in_sizes; (void)n_in; (void)out_size; (void)ws_size;
  const float* x      = (const float*)d_in[0];
  const float* eps_g0 = (const float*)d_in[1];
  const float* eps_u  = (const float*)d_in[2];
  const float* Wih_f[6]; const float* Whh_f[6]; const float* bih[6]; const float* bhh[6];
  for(int c=0;c<6;c++){
    Wih_f[c]=(const float*)d_in[3+4*c]; Whh_f[c]=(const float*)d_in[4+4*c];
    bih[c]  =(const float*)d_in[5+4*c]; bhh[c]  =(const float*)d_in[6+4*c];
  }
  const float* W_g0m=(const float*)d_in[27]; const float* b_g0m=(const float*)d_in[28];
  const float* W_g0v=(const float*)d_in[29]; const float* b_g0v=(const float*)d_in[30];
  const float* W_um =(const float*)d_in[31]; const float* b_um =(const float*)d_in[32];
  const float* W_uv =(const float*)d_in[33]; const float* b_uv =(const float*)d_in[34];
  const float* W_f  =(const float*)d_in[35]; const float* b_f  =(const float*)d_in[36];
  const float* W_r  =(const float*)d_in[37]; const float* b_r  =(const float*)d_in[38];

  char* ws = (char*)d_ws; size_t off = 0;
  auto alloc = [&](size_t bytes)->char*{
    char* p = ws + off; off = (off + bytes + 255) & ~(size_t)255; return p;
  };
  __bf16* wencall = (__bf16*)alloc((size_t)4*768*256*2);
  __bf16* whhall  = (__bf16*)alloc((size_t)4*768*256*2);
  __bf16* wct_b   = (__bf16*)alloc((size_t)384*576*2);
  __bf16* whhct_b = (__bf16*)alloc((size_t)384*128*2);
  __bf16* wihgn_b = (__bf16*)alloc((size_t)768*64*2);
  __bf16* whhgn_b = (__bf16*)alloc((size_t)768*256*2);
  __bf16* wum_b   = (__bf16*)alloc((size_t)64*128*2);
  __bf16* wuv_b   = (__bf16*)alloc((size_t)64*128*2);
  __bf16* wf_b    = (__bf16*)alloc((size_t)64*256*2);
  __bf16* henc    = (__bf16*)alloc((size_t)200*512*512*2);   // reused as epsT after gict
  __bf16* gi_buf  = (__bf16*)alloc((size_t)4*TC*768*512*2);  // reused as gictT
  float*  hcar    = (float*)alloc((size_t)4*512*256*4);
  float*  g0buf   = (float*)alloc((size_t)512*256*4);

  for(int c=0;c<4;c++){
    cvt_bf16<<<128,256,0,stream>>>(Wih_f[c], wencall + (size_t)c*768*256, 768*256);
    cvt_bf16<<<128,256,0,stream>>>(Whh_f[c], whhall  + (size_t)c*768*256, 768*256);
  }
  cvt_bf16<<<128,256,0,stream>>>(Wih_f[4], wct_b,   384*576);
  cvt_bf16<<<64 ,256,0,stream>>>(Whh_f[4], whhct_b, 384*128);
  cvt_bf16<<<64 ,256,0,stream>>>(Wih_f[5], wihgn_b, 768*64);
  cvt_bf16<<<128,256,0,stream>>>(Whh_f[5], whhgn_b, 768*256);
  cvt_bf16<<<32 ,256,0,stream>>>(W_um, wum_b, 64*128);
  cvt_bf16<<<32 ,256,0,stream>>>(W_uv, wuv_b, 64*128);
  cvt_bf16<<<32 ,256,0,stream>>>(W_f,  wf_b,  64*256);
  hipMemsetAsync(hcar, 0, (size_t)4*512*256*4, stream);

  EncP ep;
  ep.whh = whhall;
  for(int c=0;c<4;c++){ ep.bih[c]=bih[c]; ep.bhh[c]=bhh[c]; }
  ep.gi = gi_buf; ep.henc = henc; ep.hcar = hcar;
  for(int k=0;k<NCH;k++){
    gi_gemm<<<dim3((512*TC)/64,4),256,0,stream>>>(x, wencall, gi_buf, k*TC);
    ep.t0 = k*TC;
    enc_scan<<<dim3(32,4),512,0,stream>>>(ep);
  }

  float* out = (float*)d_out;
  float* o_mean = out;
  float* o_logv = out + 131072;
  float* o_um   = out + 262144;
  float* o_ul   = out + 6815744;
  float* o_f    = out + 13369344;
  float* o_r    = out + 19922944;

  g0_kernel<<<512,256,0,stream>>>(hcar + 0, hcar + (size_t)1*512*256,
                                  W_g0m,b_g0m, W_g0v,b_g0v, eps_g0,
                                  o_mean,o_logv, g0buf);
  gict_gemm<<<800,256,0,stream>>>(henc, wct_b, gi_buf);

  // henc is dead after gict_gemm: reuse its space for the eps transpose
  float* epsT = (float*)henc;
  epsT_k<<<2048,256,0,stream>>>((const float4*)eps_u, (float4*)epsT);

  GenP gp;
  gp.wct=wct_b; gp.whh_ct=whhct_b; gp.wih_gn=wihgn_b; gp.whh_gn=whhgn_b;
  gp.w_um=wum_b; gp.w_uv=wuv_b; gp.w_f=wf_b;
  gp.bih_ct=bih[4]; gp.bhh_ct=bhh[4]; gp.bih_gn=bih[5]; gp.bhh_gn=bhh[5];
  gp.b_um=b_um; gp.b_uv=b_uv; gp.b_f=b_f;
  gp.gihT=gi_buf; gp.g0=g0buf; gp.epsT=epsT;
  gp.o_um=o_um; gp.o_ul=o_ul; gp.o_f=o_f;
  gen_scan<<<32,512,0,stream>>>(gp);

  rates_k<<<8192,256,0,stream>>>(o_f, W_r, b_r, o_r);
}